// Round 4
// baseline (193.646 us; speedup 1.0000x reference)
//
#include <hip/hip_runtime.h>
#include <hip/hip_cooperative_groups.h>
#include <stdint.h>

namespace cg = cooperative_groups;

#define B_ 2
#define N_ 120000
#define C_ 80
#define K_ 300
#define MAXDET 100
#define CAP 1024        // per-image candidate capacity (mean ~150)
#define KTOP 300
#define NW 5            // ceil(KTOP/64)
#define NB 235          // filter blocks
#define TPB 256
#define SLOTS 32        // per-(image,block) slot capacity; mean ~0.64 survivors

__device__ __constant__ float SCORE_THRES_F = 0.99875f;
__device__ __constant__ float NMS_THRES_F   = 0.5f;
__device__ __constant__ float MIN_SIZE_F    = 0.001f;
__device__ __constant__ float BBOX_CLIP_F   = 4.135166556742356f; // log(1000/16) f32

// read a u64 from another lane via v_readlane (VALU latency, not DS latency)
__device__ __forceinline__ unsigned long long rl64(unsigned long long v, int lane) {
    unsigned lo = (unsigned)__builtin_amdgcn_readlane((int)(unsigned)(v & 0xffffffffull), lane);
    unsigned hi = (unsigned)__builtin_amdgcn_readlane((int)(unsigned)(v >> 32), lane);
    return ((unsigned long long)hi << 32) | lo;
}

// ---------------------------------------------------------------------------
// One cooperative kernel. Blocks 0..NB-1: fused out-init + class-0 filter
// (block-private slot compaction, no global atomics). grid.sync(). Blocks
// NB..NB+B_-1: per-image sequential per-class NMS chain.
// out layout (f32): [0,B*CK*5) out5 | [.,B*CK*6) labels | [.,B*CK*7) keep.
// ---------------------------------------------------------------------------
__global__ __launch_bounds__(TPB) void retina_fused(
    const float* __restrict__ boxp, const float* __restrict__ clsp,
    const float* __restrict__ anch, const int* __restrict__ ih,
    const int* __restrict__ iw, int* __restrict__ cnt,
    int* __restrict__ g_idx, float* __restrict__ g_sc,
    float4* __restrict__ g_bx, float* __restrict__ out) {
#pragma clang fp contract(off)
    const int blk  = blockIdx.x;
    const int ltid = threadIdx.x;

    __shared__ int lcnt[2];
    __shared__ __align__(16) float s_sc[CAP];
    __shared__ __align__(16) int   s_id[CAP];
    __shared__ float4 s_bx[CAP];
    __shared__ float  o_sc[KTOP];
    __shared__ int    o_id[KTOP];
    __shared__ float  o_ar[KTOP];
    __shared__ float  o_nsc[KTOP];
    __shared__ float4 o_bx[KTOP];
    __shared__ unsigned long long suppW[KTOP * NW];
    __shared__ unsigned long long keepm[NW];
    __shared__ int s_cnt, s_nk, s_m;
    __shared__ int wsum[4];
    __shared__ int    n_id[MAXDET];
    __shared__ float  n_sc[MAXDET];
    __shared__ float4 n_bx[MAXDET];

    // ======================= PHASE 1: filter + init =======================
    if (blk < NB) {
        const int NT  = NB * TPB;            // 60160
        const int tid = blk * TPB + ltid;
        if (ltid < 2) lcnt[ltid] = 0;

        // 4 strided class-0 score loads first (ILP, hide HBM latency)
        const int BN = B_ * N_;
        float s[4]; int t4[4];
#pragma unroll
        for (int k = 0; k < 4; ++k) {
            int t = tid + k * NT;
            t4[k] = t;
            s[k] = (t < BN) ? clsp[(size_t)t * C_] : 0.f;
        }

        // init output (coalesced), overlaps the loads above
        const int CK  = C_ * K_;
        const int L0  = B_ * CK * 5;   // 240000
        const int L1  = L0 + B_ * CK;  // 288000
        const int TOT = L1 + B_ * CK;  // 336000
        for (int i = tid; i < TOT; i += NT) {
            float v = 0.f;
            if (i >= L0 && i < L1) { int r = i - L0; v = (float)((r % CK) / K_); }
            out[i] = v;
        }
        __syncthreads();   // lcnt ready

        // decode + compact survivors into block-private slots
#pragma unroll
        for (int k = 0; k < 4; ++k) {
            int t = t4[k];
            if (t < BN && s[k] > SCORE_THRES_F) {
                int b = t / N_, n = t - b * N_;
                float W = (float)iw[0], H = (float)ih[0];
                float4 d = *(const float4*)(boxp + (size_t)t * 4);
                float4 a = *(const float4*)(anch + (size_t)n * 4);
                float wa = a.z - a.x, ha = a.w - a.y;
                float cxa = a.x + 0.5f * wa, cya = a.y + 0.5f * ha;
                float dw = fminf(d.z, BBOX_CLIP_F), dh = fminf(d.w, BBOX_CLIP_F);
                float cx = d.x * wa + cxa, cy = d.y * ha + cya;
                float w = expf(dw) * wa, h = expf(dh) * ha;
                float x1 = cx - 0.5f * w, y1 = cy - 0.5f * h;
                float x2 = cx + 0.5f * w, y2 = cy + 0.5f * h;
                x1 = fminf(fmaxf(x1, 0.f), W);
                y1 = fminf(fmaxf(y1, 0.f), H);
                x2 = fminf(fmaxf(x2, 0.f), W);
                y2 = fminf(fmaxf(y2, 0.f), H);
                if ((x2 - x1 >= MIN_SIZE_F) && (y2 - y1 >= MIN_SIZE_F)) {
                    int p = atomicAdd(&lcnt[b], 1);   // LDS atomic, block-local
                    if (p < SLOTS) {
                        int q = (b * NB + blk) * SLOTS + p;
                        g_idx[q] = n;
                        g_sc[q]  = s[k];
                        g_bx[q]  = make_float4(x1, y1, x2, y2);
                    }
                }
            }
        }
        __syncthreads();
        if (ltid < 2) cnt[ltid * NB + blk] = min(lcnt[ltid], SLOTS);
    }

    cg::this_grid().sync();
    if (blk < NB) return;

    // ======================= PHASE 2: per-image NMS =======================
    const int b   = blk - NB;
    const int tid = ltid;
    const int BS  = TPB;

    if (tid == 0) s_nk = 0;
    const size_t CK = (size_t)C_ * K_;

    for (int c = 0; c < C_; ++c) {
        if (c > 0 && s_nk == 0) break;
        if (tid == 0) s_cnt = 0;
        __syncthreads();                 // A

        int m_in;
        if (c == 0) {
            // prefix-scan the 235 per-block counts, then gather
            int lane = tid & 63, wvi = tid >> 6;
            int v = (tid < NB) ? cnt[b * NB + tid] : 0;
            int x = v;
            for (int d = 1; d < 64; d <<= 1) {
                int y = __shfl_up(x, d);
                if (lane >= d) x += y;
            }
            if (lane == 63) wsum[wvi] = x;
            __syncthreads();
            int offbase = 0;
            for (int w = 0; w < wvi; ++w) offbase += wsum[w];
            if (tid == BS - 1) s_m = offbase + x;   // grand total
            int excl = offbase + x - v;             // exclusive prefix
            for (int j = 0; j < v; ++j) {
                int dst = excl + j;
                if (dst < CAP) {
                    int src = (b * NB + tid) * SLOTS + j;
                    s_sc[dst] = g_sc[src];
                    s_id[dst] = g_idx[src];
                    s_bx[dst] = g_bx[src];
                }
            }
            __syncthreads();             // B
            m_in = min(s_m, CAP);
        } else {
            int nk = s_nk;
            for (int t = tid; t < nk; t += BS) {
                float sv = n_sc[t];      // prefetched last class — LDS only
                if (sv > SCORE_THRES_F) {
                    int p = atomicAdd(&s_cnt, 1);
                    s_sc[p] = sv; s_id[p] = n_id[t]; s_bx[p] = n_bx[t];
                }
            }
            __syncthreads();             // B
            m_in = s_cnt;
        }
        int m = min(m_in, KTOP);
        if (m == 0) {
            if (tid == 0) s_nk = 0;
            __syncthreads();
            continue;
        }

        // ---- R: rank-sort + next-class score prefetch ----
        for (int i = tid; i < m_in; i += BS) {
            float si = s_sc[i]; int di = s_id[i]; float4 bx = s_bx[i];
            float ns = 0.f;
            if (c + 1 < C_) ns = clsp[((size_t)(b * N_) + di) * C_ + (c + 1)];
            int rank = 0;
            int m4 = m_in & ~3;
            for (int j = 0; j < m4; j += 4) {
                float4 sj = *(const float4*)&s_sc[j];
                int4   dj = *(const int4*)&s_id[j];
                rank += (sj.x > si) || (sj.x == si && dj.x < di);
                rank += (sj.y > si) || (sj.y == si && dj.y < di);
                rank += (sj.z > si) || (sj.z == si && dj.z < di);
                rank += (sj.w > si) || (sj.w == si && dj.w < di);
            }
            for (int j = m4; j < m_in; ++j) {
                float sj = s_sc[j];
                rank += (sj > si) || (sj == si && s_id[j] < di);
            }
            if (rank < KTOP) {
                o_sc[rank] = si; o_id[rank] = di; o_bx[rank] = bx;
                o_ar[rank] = (bx.z - bx.x) * (bx.w - bx.y);
                o_nsc[rank] = ns;
            }
        }
        __syncthreads();                 // C

        // ---- S: suppression rows (word-segmented), 256 threads ----
        for (int i = tid; i < m; i += BS) {
            float4 bi = o_bx[i]; float ai = o_ar[i];
            for (int w = 0; w < NW; ++w) {
                unsigned long long msk = 0ull;
                int jlo = max(i + 1, w * 64);
                int jhi = min(m, w * 64 + 64);
#pragma unroll 4
                for (int j = jlo; j < jhi; ++j) {
                    float4 bj = o_bx[j];
                    float lx = fmaxf(bi.x, bj.x), ly = fmaxf(bi.y, bj.y);
                    float rx = fminf(bi.z, bj.z), ry = fminf(bi.w, bj.w);
                    float ww = fmaxf(rx - lx, 0.f), hh = fmaxf(ry - ly, 0.f);
                    float inter = ww * hh;
                    float arj = (bj.z - bj.x) * (bj.w - bj.y);
                    float iou = inter / (ai + arj - inter + 1e-9f);
                    if (iou > NMS_THRES_F) msk |= 1ull << (j & 63);
                }
                suppW[i * NW + w] = msk;
            }
        }
        __syncthreads();                 // D

        // ---- V: wave-0 register-resident sequential resolve ----
        // Lane l holds rows l, 64+l, ... in registers; the scan is wave-
        // uniform scalar code using v_readlane (short VALU chain, no DS).
        if (tid < 64) {
            const int lane = tid;
            unsigned long long row[NW][NW];
#pragma unroll
            for (int g = 0; g < NW; ++g) {
                int i = g * 64 + lane;
#pragma unroll
                for (int w = 0; w < NW; ++w)
                    row[g][w] = (w >= g && i < m) ? suppW[i * NW + w] : 0ull;
            }
            unsigned long long km[NW];
#pragma unroll
            for (int w = 0; w < NW; ++w) {
                int nb2 = m - w * 64;
                km[w] = (nb2 >= 64) ? ~0ull : (nb2 > 0 ? ((1ull << nb2) - 1ull) : 0ull);
            }
#pragma unroll
            for (int g = 0; g < NW; ++g) {
                unsigned long long pend = km[g];
                while (pend) {
                    int t = __builtin_ctzll(pend);
#pragma unroll
                    for (int w = 0; w < NW; ++w)
                        if (w >= g) km[w] &= ~rl64(row[g][w], t);
                    // row t's own bit survives (supp rows only have bits j>i)
                    pend = (t >= 63) ? 0ull : (km[g] & (~0ull << (t + 1)));
                }
            }
            // MAX_DET cap: keep lowest-rank MAXDET of the kept set (uniform)
            int cnt2 = 0;
#pragma unroll
            for (int w = 0; w < NW; ++w) {
                unsigned long long x = km[w];
                if (cnt2 >= MAXDET) { km[w] = 0ull; continue; }
                int pc = __popcll(x);
                if (cnt2 + pc > MAXDET) {
                    int need = MAXDET - cnt2;
                    unsigned long long y = x;
                    for (int k2 = 0; k2 < need; ++k2) y &= y - 1ull;
                    km[w] = x ^ y;   // keep lowest `need` set bits
                    cnt2 = MAXDET;
                } else cnt2 += pc;
            }
            if (lane == 0) {
#pragma unroll
                for (int w = 0; w < NW; ++w) keepm[w] = km[w];
                s_nk = cnt2;
            }
        }
        __syncthreads();                 // E

        // ---- W: write kept rows + build next kept list ----
        for (int r = tid; r < m; r += BS) {
            unsigned long long wv = keepm[r >> 6];
            if ((wv >> (r & 63)) & 1ull) {
                int pos = __popcll(wv & ((1ull << (r & 63)) - 1ull));
                for (int w = 0; w < (r >> 6); ++w) pos += __popcll(keepm[w]);
                size_t row_ = (size_t)b * CK + (size_t)c * K_ + r;
                float4 bx = o_bx[r];
                float* o5 = out + row_ * 5;
                o5[0] = bx.x; o5[1] = bx.y; o5[2] = bx.z; o5[3] = bx.w;
                o5[4] = o_sc[r];
                out[(size_t)B_ * CK * 6 + row_] = 1.0f;
                n_id[pos] = o_id[r];
                n_bx[pos] = bx;
                n_sc[pos] = o_nsc[r];
            }
        }
        // next iteration's barrier A protects n_* reuse
    }
}

extern "C" void kernel_launch(void* const* d_in, const int* in_sizes, int n_in,
                              void* d_out, int out_size, void* d_ws, size_t ws_size,
                              hipStream_t stream) {
    const float* boxp = (const float*)d_in[0];
    const float* clsp = (const float*)d_in[1];
    const float* anch = (const float*)d_in[2];
    const int*   ih   = (const int*)d_in[3];
    const int*   iw   = (const int*)d_in[4];
    float* outp = (float*)d_out;

    // ws layout (no zeroing needed — every used word written each call,
    // visibility across phases via grid.sync):
    //   [0, 4096)          cnt[B_][NB]
    //   [4096, +60160)     g_idx  B_*NB*SLOTS i32
    //   [64256, +60160)    g_sc   B_*NB*SLOTS f32
    //   [124416, +240640)  g_bx   B_*NB*SLOTS float4 (16B-aligned)
    int*    cnt   = (int*)d_ws;
    int*    g_idx = (int*)((char*)d_ws + 4096);
    float*  g_sc  = (float*)((char*)d_ws + 4096 + (size_t)B_ * NB * SLOTS * 4);
    float4* g_bx  = (float4*)((char*)d_ws + 4096 + (size_t)B_ * NB * SLOTS * 8);

    void* args[] = {(void*)&boxp, (void*)&clsp, (void*)&anch, (void*)&ih,
                    (void*)&iw, (void*)&cnt, (void*)&g_idx, (void*)&g_sc,
                    (void*)&g_bx, (void*)&outp};
    hipLaunchCooperativeKernel((void*)retina_fused, dim3(NB + B_), dim3(TPB),
                               args, 0, stream);
}

// Round 5
// 137.466 us; speedup vs baseline: 1.4087x; 1.4087x over previous
//
#include <hip/hip_runtime.h>
#include <stdint.h>

#define B_ 2
#define N_ 120000
#define C_ 80
#define K_ 300
#define MAXDET 100
#define CAP 1024        // per-image candidate capacity (mean ~150)
#define KTOP 300
#define NW 5            // ceil(KTOP/64)
#define NB 235          // filter blocks
#define TPB 256
#define SLOTS 32        // per-(image,block) slot capacity; mean ~0.64 survivors

__device__ __constant__ float SCORE_THRES_F = 0.99875f;
__device__ __constant__ float NMS_THRES_F   = 0.5f;
__device__ __constant__ float MIN_SIZE_F    = 0.001f;
__device__ __constant__ float BBOX_CLIP_F   = 4.135166556742356f; // log(1000/16) f32

// read a u64 from another lane via v_readlane (VALU latency, not DS latency)
__device__ __forceinline__ unsigned long long rl64(unsigned long long v, int lane) {
    unsigned lo = (unsigned)__builtin_amdgcn_readlane((int)(unsigned)(v & 0xffffffffull), lane);
    unsigned hi = (unsigned)__builtin_amdgcn_readlane((int)(unsigned)(v >> 32), lane);
    return ((unsigned long long)hi << 32) | lo;
}

// ---------------------------------------------------------------------------
// fused init + class-0 filter, poison-proof (no global counter init needed):
// block-private slot compaction via LDS counter; count written
// unconditionally. Score loads issued first to hide HBM latency.
// out layout (f32): [0,B*CK*5) out5 | [.,B*CK*6) labels | [.,B*CK*7) keep.
// ---------------------------------------------------------------------------
__global__ __launch_bounds__(TPB) void filter_init(
    const float* __restrict__ boxp, const float* __restrict__ clsp,
    const float* __restrict__ anch, const int* __restrict__ ih,
    const int* __restrict__ iw, int* __restrict__ cnt,
    int* __restrict__ g_idx, float* __restrict__ g_sc,
    float4* __restrict__ g_bx, float* __restrict__ out) {
#pragma clang fp contract(off)
    __shared__ int lcnt[2];
    const int blk = blockIdx.x;
    const int ltid = threadIdx.x;
    const int NT  = NB * TPB;            // 60160
    const int tid = blk * TPB + ltid;
    if (ltid < 2) lcnt[ltid] = 0;

    // 4 strided class-0 score loads first (ILP)
    const int BN = B_ * N_;
    float s[4]; int t4[4];
#pragma unroll
    for (int k = 0; k < 4; ++k) {
        int t = tid + k * NT;
        t4[k] = t;
        s[k] = (t < BN) ? clsp[(size_t)t * C_] : 0.f;
    }

    // init output (coalesced), overlaps the loads above
    const int CK  = C_ * K_;
    const int L0  = B_ * CK * 5;   // 240000
    const int L1  = L0 + B_ * CK;  // 288000
    const int TOT = L1 + B_ * CK;  // 336000
    for (int i = tid; i < TOT; i += NT) {
        float v = 0.f;
        if (i >= L0 && i < L1) { int r = i - L0; v = (float)((r % CK) / K_); }
        out[i] = v;
    }
    __syncthreads();   // lcnt ready

    // decode + compact survivors into block-private slots
#pragma unroll
    for (int k = 0; k < 4; ++k) {
        int t = t4[k];
        if (t < BN && s[k] > SCORE_THRES_F) {
            int b = t / N_, n = t - b * N_;
            float W = (float)iw[0], H = (float)ih[0];
            float4 d = *(const float4*)(boxp + (size_t)t * 4);
            float4 a = *(const float4*)(anch + (size_t)n * 4);
            float wa = a.z - a.x, ha = a.w - a.y;
            float cxa = a.x + 0.5f * wa, cya = a.y + 0.5f * ha;
            float dw = fminf(d.z, BBOX_CLIP_F), dh = fminf(d.w, BBOX_CLIP_F);
            float cx = d.x * wa + cxa, cy = d.y * ha + cya;
            float w = expf(dw) * wa, h = expf(dh) * ha;
            float x1 = cx - 0.5f * w, y1 = cy - 0.5f * h;
            float x2 = cx + 0.5f * w, y2 = cy + 0.5f * h;
            x1 = fminf(fmaxf(x1, 0.f), W);
            y1 = fminf(fmaxf(y1, 0.f), H);
            x2 = fminf(fmaxf(x2, 0.f), W);
            y2 = fminf(fmaxf(y2, 0.f), H);
            if ((x2 - x1 >= MIN_SIZE_F) && (y2 - y1 >= MIN_SIZE_F)) {
                int p = atomicAdd(&lcnt[b], 1);   // LDS atomic, block-local
                if (p < SLOTS) {
                    int q = (b * NB + blk) * SLOTS + p;
                    g_idx[q] = n;
                    g_sc[q]  = s[k];
                    g_bx[q]  = make_float4(x1, y1, x2, y2);
                }
            }
        }
    }
    __syncthreads();
    if (ltid < 2) cnt[ltid * NB + blk] = min(lcnt[ltid], SLOTS);  // unconditional
}

// ---------------------------------------------------------------------------
// sequential per-class chain, one block per image.
// Class 0 gathers via shfl prefix-scan of the 235 per-block counts. Per class:
// rank-sort (4x unrolled LDS scan, lax.top_k tie-break) -> supp rows, words
// bounded by runtime mw -> wave-0 register-resident resolve with readlane +
// ballot nonzero-row skip -> MAX_DET cap -> write. Next-class scores
// prefetched during rank phase.
// ---------------------------------------------------------------------------
__global__ __launch_bounds__(TPB) void seq_nms(const float* __restrict__ clsp,
                                               const int* __restrict__ cnt,
                                               const int* __restrict__ g_idx,
                                               const float* __restrict__ g_sc,
                                               const float4* __restrict__ g_bx,
                                               float* __restrict__ out) {
#pragma clang fp contract(off)
    const int b   = blockIdx.x;
    const int tid = threadIdx.x;
    const int BS  = blockDim.x;

    __shared__ __align__(16) float s_sc[CAP];
    __shared__ __align__(16) int   s_id[CAP];
    __shared__ float4 s_bx[CAP];
    __shared__ float  o_sc[KTOP];
    __shared__ int    o_id[KTOP];
    __shared__ float  o_ar[KTOP];
    __shared__ float  o_nsc[KTOP];
    __shared__ float4 o_bx[KTOP];
    __shared__ unsigned long long suppW[KTOP * NW];
    __shared__ unsigned long long keepm[NW];
    __shared__ int s_cnt, s_nk, s_m;
    __shared__ int wsum[4];
    __shared__ int    n_id[MAXDET];
    __shared__ float  n_sc[MAXDET];
    __shared__ float4 n_bx[MAXDET];

    if (tid == 0) s_nk = 0;
    const size_t CK = (size_t)C_ * K_;

    for (int c = 0; c < C_; ++c) {
        if (c > 0 && s_nk == 0) break;
        if (tid == 0) s_cnt = 0;
        __syncthreads();                 // A

        int m_in;
        if (c == 0) {
            // prefix-scan the 235 per-block counts, then gather
            int lane = tid & 63, wvi = tid >> 6;
            int v = (tid < NB) ? cnt[b * NB + tid] : 0;
            int x = v;
            for (int d = 1; d < 64; d <<= 1) {
                int y = __shfl_up(x, d);
                if (lane >= d) x += y;
            }
            if (lane == 63) wsum[wvi] = x;
            __syncthreads();
            int offbase = 0;
            for (int w = 0; w < wvi; ++w) offbase += wsum[w];
            if (tid == BS - 1) s_m = offbase + x;   // grand total
            int excl = offbase + x - v;             // exclusive prefix
            for (int j = 0; j < v; ++j) {
                int dst = excl + j;
                if (dst < CAP) {
                    int src = (b * NB + tid) * SLOTS + j;
                    s_sc[dst] = g_sc[src];
                    s_id[dst] = g_idx[src];
                    s_bx[dst] = g_bx[src];
                }
            }
            __syncthreads();             // B
            m_in = min(s_m, CAP);
        } else {
            int nk = s_nk;
            for (int t = tid; t < nk; t += BS) {
                float sv = n_sc[t];      // prefetched last class — LDS only
                if (sv > SCORE_THRES_F) {
                    int p = atomicAdd(&s_cnt, 1);
                    s_sc[p] = sv; s_id[p] = n_id[t]; s_bx[p] = n_bx[t];
                }
            }
            __syncthreads();             // B
            m_in = s_cnt;
        }
        int m = min(m_in, KTOP);
        if (m == 0) {
            if (tid == 0) s_nk = 0;
            __syncthreads();
            continue;
        }
        const int mw = (m + 63) >> 6;    // live 64-bit words (<= NW)

        // ---- R: rank-sort + next-class score prefetch ----
        for (int i = tid; i < m_in; i += BS) {
            float si = s_sc[i]; int di = s_id[i]; float4 bx = s_bx[i];
            float ns = 0.f;
            if (c + 1 < C_) ns = clsp[((size_t)(b * N_) + di) * C_ + (c + 1)];
            int rank = 0;
            int m4 = m_in & ~3;
            for (int j = 0; j < m4; j += 4) {
                float4 sj = *(const float4*)&s_sc[j];
                int4   dj = *(const int4*)&s_id[j];
                rank += (sj.x > si) || (sj.x == si && dj.x < di);
                rank += (sj.y > si) || (sj.y == si && dj.y < di);
                rank += (sj.z > si) || (sj.z == si && dj.z < di);
                rank += (sj.w > si) || (sj.w == si && dj.w < di);
            }
            for (int j = m4; j < m_in; ++j) {
                float sj = s_sc[j];
                rank += (sj > si) || (sj == si && s_id[j] < di);
            }
            if (rank < KTOP) {
                o_sc[rank] = si; o_id[rank] = di; o_bx[rank] = bx;
                o_ar[rank] = (bx.z - bx.x) * (bx.w - bx.y);
                o_nsc[rank] = ns;
            }
        }
        __syncthreads();                 // C

        // ---- S: suppression rows, words bounded by mw ----
        for (int i = tid; i < m; i += BS) {
            float4 bi = o_bx[i]; float ai = o_ar[i];
            for (int w = 0; w < mw; ++w) {
                unsigned long long msk = 0ull;
                int jlo = max(i + 1, w * 64);
                int jhi = min(m, w * 64 + 64);
#pragma unroll 4
                for (int j = jlo; j < jhi; ++j) {
                    float4 bj = o_bx[j];
                    float lx = fmaxf(bi.x, bj.x), ly = fmaxf(bi.y, bj.y);
                    float rx = fminf(bi.z, bj.z), ry = fminf(bi.w, bj.w);
                    float ww = fmaxf(rx - lx, 0.f), hh = fmaxf(ry - ly, 0.f);
                    float inter = ww * hh;
                    float arj = (bj.z - bj.x) * (bj.w - bj.y);
                    float iou = inter / (ai + arj - inter + 1e-9f);
                    if (iou > NMS_THRES_F) msk |= 1ull << (j & 63);
                }
                suppW[i * NW + w] = msk;
            }
        }
        __syncthreads();                 // D

        // ---- V: wave-0 register-resident resolve, nz-skip via ballot ----
        if (tid < 64) {
            const int lane = tid;
            unsigned long long row[NW][NW];
            unsigned long long nz[NW];
#pragma unroll
            for (int g = 0; g < NW; ++g) {
                int i = g * 64 + lane;
                unsigned long long h = 0ull;
#pragma unroll
                for (int w = 0; w < NW; ++w) {
                    unsigned long long v2 = 0ull;
                    if (w >= g && w < mw && i < m) v2 = suppW[i * NW + w];
                    row[g][w] = v2; h |= v2;
                }
                nz[g] = __ballot(h != 0ull);   // rows in group g that suppress
            }
            unsigned long long km[NW];
#pragma unroll
            for (int w = 0; w < NW; ++w) {
                int nb2 = m - w * 64;
                km[w] = (nb2 >= 64) ? ~0ull : (nb2 > 0 ? ((1ull << nb2) - 1ull) : 0ull);
            }
#pragma unroll
            for (int g = 0; g < NW; ++g) {
                if (g >= mw) break;
                unsigned long long pend = km[g] & nz[g];
                while (pend) {
                    int t = __builtin_ctzll(pend);
#pragma unroll
                    for (int w = 0; w < NW; ++w)
                        if (w >= g) { if (w < mw) km[w] &= ~rl64(row[g][w], t); }
                    unsigned long long hi = (t >= 63) ? 0ull : (~0ull << (t + 1));
                    pend = km[g] & nz[g] & hi;   // row t's own bit survives
                }
            }
            // MAX_DET cap: keep lowest-rank MAXDET of the kept set (uniform)
            int cnt2 = 0;
#pragma unroll
            for (int w = 0; w < NW; ++w) {
                unsigned long long x = km[w];
                if (cnt2 >= MAXDET) { km[w] = 0ull; continue; }
                int pc = __popcll(x);
                if (cnt2 + pc > MAXDET) {
                    int need = MAXDET - cnt2;
                    unsigned long long y = x;
                    for (int k2 = 0; k2 < need; ++k2) y &= y - 1ull;
                    km[w] = x ^ y;   // keep lowest `need` set bits
                    cnt2 = MAXDET;
                } else cnt2 += pc;
            }
            if (lane == 0) {
#pragma unroll
                for (int w = 0; w < NW; ++w) keepm[w] = km[w];
                s_nk = cnt2;
            }
        }
        __syncthreads();                 // E

        // ---- W: write kept rows + build next kept list ----
        for (int r = tid; r < m; r += BS) {
            unsigned long long wv = keepm[r >> 6];
            if ((wv >> (r & 63)) & 1ull) {
                int pos = __popcll(wv & ((1ull << (r & 63)) - 1ull));
                for (int w = 0; w < (r >> 6); ++w) pos += __popcll(keepm[w]);
                size_t row_ = (size_t)b * CK + (size_t)c * K_ + r;
                float4 bx = o_bx[r];
                float* o5 = out + row_ * 5;
                o5[0] = bx.x; o5[1] = bx.y; o5[2] = bx.z; o5[3] = bx.w;
                o5[4] = o_sc[r];
                out[(size_t)B_ * CK * 6 + row_] = 1.0f;
                n_id[pos] = o_id[r];
                n_bx[pos] = bx;
                n_sc[pos] = o_nsc[r];
            }
        }
        // next iteration's barrier A protects n_* reuse
    }
}

extern "C" void kernel_launch(void* const* d_in, const int* in_sizes, int n_in,
                              void* d_out, int out_size, void* d_ws, size_t ws_size,
                              hipStream_t stream) {
    const float* boxp = (const float*)d_in[0];
    const float* clsp = (const float*)d_in[1];
    const float* anch = (const float*)d_in[2];
    const int*   ih   = (const int*)d_in[3];
    const int*   iw   = (const int*)d_in[4];
    float* out = (float*)d_out;

    // ws layout (no zeroing needed — every used word written each call):
    //   [0, 4096)          cnt[B_][NB]
    //   [4096, +60160)     g_idx  B_*NB*SLOTS i32
    //   [64256, +60160)    g_sc   B_*NB*SLOTS f32
    //   [124416, +240640)  g_bx   B_*NB*SLOTS float4 (16B-aligned)
    int*    cnt   = (int*)d_ws;
    int*    g_idx = (int*)((char*)d_ws + 4096);
    float*  g_sc  = (float*)((char*)d_ws + 4096 + (size_t)B_ * NB * SLOTS * 4);
    float4* g_bx  = (float4*)((char*)d_ws + 4096 + (size_t)B_ * NB * SLOTS * 8);

    filter_init<<<NB, TPB, 0, stream>>>(boxp, clsp, anch, ih, iw,
                                        cnt, g_idx, g_sc, g_bx, out);
    seq_nms<<<B_, TPB, 0, stream>>>(clsp, cnt, g_idx, g_sc, g_bx, out);
}